// Round 11
// baseline (306.598 us; speedup 1.0000x reference)
//
#include <hip/hip_runtime.h>
#include <hip/hip_bf16.h>
#include <cstddef>

#define N_NODES 50000
#define N_EDGES 1600000
#define IN_DIM 128
#define OUT_DIM 16
#define N_HEADS 8
#define QKV_DIM 128               // N_HEADS * OUT_DIM
#define HS_STRIDE 136             // padded LDS row stride for h staging (u16)
#define OS_STRIDE 392             // padded LDS row stride for out staging (u16)

#define NBKT 782                  // ceil(50000/64) buckets of 64 dst nodes
#define NBKT_PAD 784
#define BCAP 2560                 // slots/bucket: lambda=2046, +11 sigma
#define BH_CHUNK 16384            // edges per block in scatter
#define BH_BLOCKS 98              // 98*16384 >= 1.6M

typedef __hip_bfloat16 bf16;
typedef short bf16x8 __attribute__((ext_vector_type(8)));
typedef float f32x4  __attribute__((ext_vector_type(4)));

__device__ __forceinline__ float b2f(bf16 x) { return __bfloat162float(x); }

__device__ __forceinline__ float u16tof(unsigned int u) {
    unsigned int x = u << 16;
    float f;
    __builtin_memcpy(&f, &x, 4);
    return f;
}

__device__ __forceinline__ unsigned short f2bf(float v) {
    bf16 b = __float2bfloat16(v);
    unsigned short u;
    __builtin_memcpy(&u, &b, 2);
    return u;
}

// ---------------------------------------------------------------------------
// fused init + dtype detect
// ---------------------------------------------------------------------------
__global__ __launch_bounds__(256) void init_detect_kernel(
    int* __restrict__ p, int nz_words,
    const unsigned short* __restrict__ hraw, int* __restrict__ flag, int nblocks)
{
    __shared__ int red[256];
    int t = threadIdx.x;
    if ((int)blockIdx.x == nblocks - 1) {
        int cnt = 0;
        for (int i = t; i < 8192; i += 256) {
            unsigned short u = hraw[i];
            int e = (u >> 7) & 0xFF;
            if (e == 0xFF || e > 0x85 || (e == 0 && (u & 0x7F) != 0)) cnt++;
        }
        red[t] = cnt;
        __syncthreads();
        for (int s = 128; s > 0; s >>= 1) {
            if (t < s) red[t] += red[t + s];
            __syncthreads();
        }
        if (t == 0) *flag = red[0];
    } else {
        int i = blockIdx.x * 256 + t;
        if (i < nz_words) p[i] = 0;
    }
}

__global__ __launch_bounds__(256) void sentinel_kernel(unsigned short* __restrict__ out, int n) {
    int i = blockIdx.x * 256 + threadIdx.x;
    if (i < n) out[i] = 0x42C8;
}

// ---------------------------------------------------------------------------
// prep: repack Wq|Wk|Wv into MFMA B-fragment order + fp32 bias vector.
// ---------------------------------------------------------------------------
__global__ __launch_bounds__(256) void prep_kernel(
    const void* __restrict__ Wqr, const void* __restrict__ bqr,
    const void* __restrict__ Wkr, const void* __restrict__ bkr,
    const void* __restrict__ Wvr, const void* __restrict__ bvr,
    const int* __restrict__ flag,
    unsigned short* __restrict__ Wfrag, float* __restrict__ bias_f)
{
    const bool f32 = (*flag > 100);
    int tid = blockIdx.x * 256 + threadIdx.x;

    if (tid < 384) {
        int mat = tid >> 7, c = tid & 127;
        const void* bp = (mat == 0) ? bqr : (mat == 1) ? bkr : bvr;
        bias_f[tid] = f32 ? ((const float*)bp)[c] : b2f(((const bf16*)bp)[c]);
    }
    if (tid >= 6144) return;

    int l  = tid & 63;
    int s  = (tid >> 6) & 3;
    int nt = tid >> 8;
    int n  = nt * 16 + (l & 15);
    int k0 = s * 32 + (l >> 4) * 8;
    int mat = n >> 7, c = n & 127;
    const void* Wp = (mat == 0) ? Wqr : (mat == 1) ? Wkr : Wvr;

    unsigned short v[8];
#pragma unroll
    for (int j = 0; j < 8; ++j) {
        int k = k0 + j;
        float w = f32 ? ((const float*)Wp)[k * QKV_DIM + c]
                      : b2f(((const bf16*)Wp)[k * QKV_DIM + c]);
        v[j] = f2bf(w);
    }
    ushort4* o = (ushort4*)(Wfrag + (size_t)tid * 8);
    o[0] = make_ushort4(v[0], v[1], v[2], v[3]);
    o[1] = make_ushort4(v[4], v[5], v[6], v[7]);
}

// ---------------------------------------------------------------------------
// MFMA projection GEMM: [50000 x 128] @ [128 x 384].
// Qt: u16[row*128+c].  KVt 32-lane interleave (lane hl: uint4 = dims 4hl..4hl+3
// of K then V). Epilogue staged via LDS, coalesced uint4 copy-out.
// ---------------------------------------------------------------------------
__global__ __launch_bounds__(256) void gemm_kernel(
    const void* __restrict__ hraw,
    const unsigned short* __restrict__ Wfrag, const float* __restrict__ bias_f,
    const int* __restrict__ flag,
    unsigned short* __restrict__ Qt, unsigned short* __restrict__ KVt)
{
    __shared__ __align__(16) unsigned short smem[64 * OS_STRIDE];   // 50,176 B

    const bool f32 = (*flag > 100);
    const int m0  = blockIdx.x * 64;
    const int tid = threadIdx.x;

#pragma unroll
    for (int it = 0; it < 8; ++it) {
        int idx = it * 1024 + tid * 4;
        int r = idx >> 7, k = idx & 127;
        int row = m0 + r;
        ushort4 w4 = make_ushort4(0, 0, 0, 0);
        if (row < N_NODES) {
            if (f32) {
                float4 v4 = ((const float4*)hraw)[(size_t)row * 32 + (k >> 2)];
                w4 = make_ushort4(f2bf(v4.x), f2bf(v4.y), f2bf(v4.z), f2bf(v4.w));
            } else {
                uint2 u = ((const uint2*)hraw)[(size_t)row * 32 + (k >> 2)];
                w4 = make_ushort4((unsigned short)(u.x & 0xffffu), (unsigned short)(u.x >> 16),
                                  (unsigned short)(u.y & 0xffffu), (unsigned short)(u.y >> 16));
            }
        }
        *(ushort4*)&smem[r * HS_STRIDE + k] = w4;
    }
    __syncthreads();

    const int lane = tid & 63;
    const int wave = tid >> 6;
    const int qd   = lane >> 4;
    const int ln15 = lane & 15;

    bf16x8 afr[4][4];
#pragma unroll
    for (int ms = 0; ms < 4; ++ms)
#pragma unroll
        for (int s = 0; s < 4; ++s)
            afr[ms][s] = *(const bf16x8*)&smem[(ms * 16 + ln15) * HS_STRIDE + s * 32 + qd * 8];

    __syncthreads();   // smem reused for output staging

#pragma unroll
    for (int i = 0; i < 6; ++i) {
        const int nt  = wave + i * 4;
        const int col = nt * 16 + ln15;
        const float bs = bias_f[col];
        const int mat = col >> 7, c127 = col & 127;
        const int ocol = (mat == 0) ? c127
                       : 128 + 8 * (c127 >> 2) + (c127 & 3) + ((mat == 2) ? 4 : 0);

        bf16x8 bfr[4];
#pragma unroll
        for (int s = 0; s < 4; ++s)
            bfr[s] = *(const bf16x8*)(Wfrag + ((size_t)(nt * 4 + s) * 64 + lane) * 8);

#pragma unroll
        for (int ms = 0; ms < 4; ++ms) {
            f32x4 acc = {0.f, 0.f, 0.f, 0.f};
#pragma unroll
            for (int s = 0; s < 4; ++s)
                acc = __builtin_amdgcn_mfma_f32_16x16x32_bf16(afr[ms][s], bfr[s], acc, 0, 0, 0);
#pragma unroll
            for (int r = 0; r < 4; ++r) {
                int rl = ms * 16 + qd * 4 + r;
                smem[rl * OS_STRIDE + ocol] = f2bf(acc[r] + bs);
            }
        }
    }
    __syncthreads();

    for (int q = tid; q < 1024; q += 256) {
        int row = q >> 4, c = q & 15;
        int grow = m0 + row;
        if (grow < N_NODES)
            ((uint4*)Qt)[grow * 16 + c] = *(const uint4*)&smem[row * OS_STRIDE + c * 8];
    }
    for (int q = tid; q < 2048; q += 256) {
        int row = q >> 5, g = q & 31;
        int grow = m0 + row;
        if (grow < N_NODES)
            ((uint4*)KVt)[grow * 32 + g] = *(const uint4*)&smem[row * OS_STRIDE + 128 + g * 8];
    }
}

// ---------------------------------------------------------------------------
// Single-pass padded scatter over 64-node buckets (dst>>6).
// Per-block per-bucket runs ~21 edges (~84 B) -> dense-ish line writes.
// packed = src (16b) | dst_local (6b) << 16.
// ---------------------------------------------------------------------------
__global__ __launch_bounds__(256) void scatter_kernel(const int* __restrict__ src,
                                                      const int* __restrict__ dst,
                                                      int* __restrict__ gcursor,
                                                      unsigned int* __restrict__ packed) {
    __shared__ int lcnt[NBKT];
    __shared__ int lbase[NBKT];
    int t = threadIdx.x;
    for (int i = t; i < NBKT; i += 256) lcnt[i] = 0;
    __syncthreads();
    int base = blockIdx.x * BH_CHUNK;
    for (int i = 0; i < 64; ++i) {
        int e = base + i * 256 + t;
        if (e < N_EDGES) atomicAdd(&lcnt[dst[e] >> 6], 1);
    }
    __syncthreads();
    for (int i = t; i < NBKT; i += 256) {
        int c = lcnt[i];
        lbase[i] = c ? atomicAdd(&gcursor[i], c) : 0;
        lcnt[i] = 0;
    }
    __syncthreads();
    for (int i = 0; i < 64; ++i) {
        int e = base + i * 256 + t;
        if (e < N_EDGES) {
            int d = dst[e];
            int b = d >> 6;
            int pos = lbase[b] + atomicAdd(&lcnt[b], 1);
            if (pos < BCAP)
                packed[b * BCAP + pos] = (unsigned int)src[e] | ((unsigned int)(d & 63) << 16);
        }
    }
}

// ---------------------------------------------------------------------------
// Fused bucket sort + gather aggregation. One block (512 thr = 8 waves) per
// 64-dst bucket. LDS counting sort (64 counters), then 8 waves x 8 dst.
// 2 edges per wave-instruction; 8 dwordx4 nominally in flight.
// ---------------------------------------------------------------------------
__global__ __launch_bounds__(512, 4) void bucket_agg_kernel(
    const unsigned short* __restrict__ Qt, const unsigned short* __restrict__ KVt,
    const unsigned int* __restrict__ packed, const int* __restrict__ gcursor,
    const int* __restrict__ flag, void* __restrict__ out)
{
    __shared__ unsigned int   lds_pk[BCAP];     // 10 KB
    __shared__ unsigned short lds_src[BCAP];    // 5 KB
    __shared__ int cnt64[64], base64[64], cur64[64];

    const int sb = blockIdx.x;
    const int t  = threadIdx.x;
    const int nb = min(gcursor[sb], BCAP);

    if (t < 64) { cnt64[t] = 0; cur64[t] = 0; }
    __syncthreads();

    for (int j = t; j < nb; j += 512) {
        unsigned int pk = packed[sb * BCAP + j];
        lds_pk[j] = pk;
        atomicAdd(&cnt64[(pk >> 16) & 63], 1);
    }
    __syncthreads();
    if (t == 0) {
        int acc = 0;
#pragma unroll
        for (int i = 0; i < 64; ++i) { base64[i] = acc; acc += cnt64[i]; }
    }
    __syncthreads();
    for (int j = t; j < nb; j += 512) {
        unsigned int pk = lds_pk[j];
        int dl = (pk >> 16) & 63;
        int pos = base64[dl] + atomicAdd(&cur64[dl], 1);
        lds_src[pos] = (unsigned short)(pk & 0xffffu);
    }
    __syncthreads();

    const int wave = t >> 6;               // 0..7
    const int lane = t & 63;
    const int half = lane >> 5;            // 0 = even edge, 1 = odd edge
    const int hl   = lane & 31;            // dims 4hl..4hl+3
    const uint4* KV4 = (const uint4*)KVt;  // [row*32 + hl]
    const bool of32 = (*flag > 100);

    for (int dl = wave; dl < 64; dl += 8) {
        const int d = sb * 64 + dl;
        if (d >= N_NODES) continue;
        uint2 qw = ((const uint2*)Qt)[d * 32 + hl];
        const float q0 = u16tof(qw.x & 0xffffu), q1 = u16tof(qw.x >> 16);
        const float q2 = u16tof(qw.y & 0xffffu), q3 = u16tof(qw.y >> 16);
        const int off = base64[dl];
        const int n   = cnt64[dl];

        float a0 = 0.f, a1 = 0.f, a2 = 0.f, a3 = 0.f, zz = 0.f;

#define CONSUME(KV, SCMASK)                                                     \
        {                                                                       \
            float p = fmaf(u16tof((KV).x & 0xffffu), q0,                        \
                      fmaf(u16tof((KV).x >> 16), q1,                            \
                      fmaf(u16tof((KV).y & 0xffffu), q2,                        \
                           u16tof((KV).y >> 16) * q3)));                        \
            p += __shfl_xor(p, 1);                                              \
            p += __shfl_xor(p, 2);                                              \
            float sc = __expf(__builtin_amdgcn_fmed3f(p * 0.25f, -5.f, 5.f));   \
            sc *= (SCMASK);                                                     \
            a0 = fmaf(u16tof((KV).z & 0xffffu), sc, a0);                        \
            a1 = fmaf(u16tof((KV).z >> 16),     sc, a1);                        \
            a2 = fmaf(u16tof((KV).w & 0xffffu), sc, a2);                        \
            a3 = fmaf(u16tof((KV).w >> 16),     sc, a3);                        \
            zz += sc;                                                           \
        }

        int j = 0;
        for (; j + 16 <= n; j += 16) {
            int e[8];
#pragma unroll
            for (int u = 0; u < 8; ++u) e[u] = lds_src[off + j + 2 * u + half];
            uint4 kv[8];
#pragma unroll
            for (int u = 0; u < 8; ++u) kv[u] = KV4[e[u] * 32 + hl];
#pragma unroll
            for (int u = 0; u < 8; ++u) CONSUME(kv[u], 1.f)
        }
        if (j + 8 <= n) {
            int e[4];
#pragma unroll
            for (int u = 0; u < 4; ++u) e[u] = lds_src[off + j + 2 * u + half];
            uint4 kv[4];
#pragma unroll
            for (int u = 0; u < 4; ++u) kv[u] = KV4[e[u] * 32 + hl];
#pragma unroll
            for (int u = 0; u < 4; ++u) CONSUME(kv[u], 1.f)
            j += 8;
        }
        for (; j + 2 <= n; j += 2) {
            int e = lds_src[off + j + half];
            uint4 kv = KV4[e * 32 + hl];
            CONSUME(kv, 1.f)
        }
        if (j < n) {
            int e = lds_src[off + j];
            uint4 kv = KV4[e * 32 + hl];
            CONSUME(kv, (half == 0) ? 1.f : 0.f)
        }
#undef CONSUME

        a0 += __shfl_xor(a0, 32);
        a1 += __shfl_xor(a1, 32);
        a2 += __shfl_xor(a2, 32);
        a3 += __shfl_xor(a3, 32);
        zz += __shfl_xor(zz, 32);

        const float inv = 1.f / (zz + 1e-6f);
        const float r0 = a0 * inv, r1 = a1 * inv, r2 = a2 * inv, r3 = a3 * inv;

        if (half == 0) {
            if (of32) {
                ((float4*)out)[d * 32 + hl] = make_float4(r0, r1, r2, r3);
            } else {
                unsigned int w0 = ((unsigned int)f2bf(r1) << 16) | f2bf(r0);
                unsigned int w1 = ((unsigned int)f2bf(r3) << 16) | f2bf(r2);
                ((uint2*)out)[d * 32 + hl] = make_uint2(w0, w1);
            }
        }
    }
}

// ---------------------------------------------------------------------------
extern "C" void kernel_launch(void* const* d_in, const int* in_sizes, int n_in,
                              void* d_out, int out_size, void* d_ws, size_t ws_size,
                              hipStream_t stream)
{
    const void* h  = d_in[0];
    const void* Wq = d_in[1];
    const void* bq = d_in[2];
    const void* Wk = d_in[3];
    const void* bk = d_in[4];
    const void* Wv = d_in[5];
    const void* bv = d_in[6];
    const int*  src = (const int*)d_in[7];
    const int*  dst = (const int*)d_in[8];

    const size_t NQ = (size_t)N_NODES * QKV_DIM;   // 6,400,000
    const size_t WFRAG_N = 24 * 4 * 64 * 8;        // 49,152

    // ws layout:
    //  [Qt u16 NQ][KVt u16 2*NQ]                        38.4 MB
    //  [Wfrag u16 WFRAG_N][bias_f f32 384]
    //  [gcursor int NBKT_PAD][flag int 16]
    //  [packed u32 NBKT*BCAP]                           8.0 MB
    const size_t need = 3 * NQ * 2 + WFRAG_N * 2 + 384 * 4
                      + ((size_t)NBKT_PAD + 16) * sizeof(int)
                      + (size_t)NBKT * BCAP * 4;

    if (ws_size < need) {
        sentinel_kernel<<<(out_size + 255) / 256, 256, 0, stream>>>((unsigned short*)d_out, out_size);
        return;
    }

    unsigned short* Qt  = (unsigned short*)d_ws;
    unsigned short* KVt = Qt + NQ;
    unsigned short* Wfrag = KVt + 2 * NQ;
    float* bias_f = (float*)(Wfrag + WFRAG_N);
    int* gcursor = (int*)(bias_f + 384);
    int* flag    = gcursor + NBKT_PAD;
    unsigned int* packed = (unsigned int*)(flag + 16);

    const int nz = NBKT_PAD;                       // gcursor words to zero
    const int id_blocks = (nz + 255) / 256 + 1;    // + 1 detect block
    init_detect_kernel<<<id_blocks, 256, 0, stream>>>(gcursor, nz,
        (const unsigned short*)h, flag, id_blocks);

    prep_kernel<<<24, 256, 0, stream>>>(Wq, bq, Wk, bk, Wv, bv, flag, Wfrag, bias_f);

    const int gemm_blocks = (N_NODES + 63) / 64;               // 782
    gemm_kernel<<<gemm_blocks, 256, 0, stream>>>(h, Wfrag, bias_f, flag, Qt, KVt);

    scatter_kernel<<<BH_BLOCKS, 256, 0, stream>>>(src, dst, gcursor, packed);

    bucket_agg_kernel<<<NBKT, 512, 0, stream>>>(Qt, KVt, packed, gcursor, flag, d_out);
}

// Round 12
// 292.575 us; speedup vs baseline: 1.0479x; 1.0479x over previous
//
#include <hip/hip_runtime.h>
#include <hip/hip_bf16.h>
#include <cstddef>

#define N_NODES 50000
#define N_EDGES 1600000
#define IN_DIM 128
#define OUT_DIM 16
#define N_HEADS 8
#define QKV_DIM 128               // N_HEADS * OUT_DIM
#define HS_STRIDE 136             // padded LDS row stride for h staging (u16)
#define OS_STRIDE 392             // padded LDS row stride for out staging (u16)

#define SUBB 3125                 // N_NODES/16 sub-buckets (16 dst nodes each)
#define SUBB_PAD 3136
#define BCAP 1024                 // slots per sub-bucket (lambda=512, >20 sigma)
#define BH_CHUNK 16384            // edges per block in scatter
#define BH_BLOCKS 98              // 98*16384 >= 1.6M

typedef __hip_bfloat16 bf16;
typedef short bf16x8 __attribute__((ext_vector_type(8)));
typedef float f32x4  __attribute__((ext_vector_type(4)));

__device__ __forceinline__ float b2f(bf16 x) { return __bfloat162float(x); }

__device__ __forceinline__ float u16tof(unsigned int u) {
    unsigned int x = u << 16;
    float f;
    __builtin_memcpy(&f, &x, 4);
    return f;
}

__device__ __forceinline__ unsigned short f2bf(float v) {
    bf16 b = __float2bfloat16(v);
    unsigned short u;
    __builtin_memcpy(&u, &b, 2);
    return u;
}

__global__ __launch_bounds__(256) void sentinel_kernel(unsigned short* __restrict__ out, int n) {
    int i = blockIdx.x * 256 + threadIdx.x;
    if (i < n) out[i] = 0x42C8;
}

// ---------------------------------------------------------------------------
// prep: self-probe input dtype (bf16-impossible bit patterns in first 8192
// u16 of h; fp32 -> ~1960 hits, bf16 -> 0), publish flag, zero gcursor,
// then repack Wq|Wk|Wv into MFMA B-fragment order + fp32 bias vector.
// 24 blocks x 256 = 6144 threads, one per (nt,s,lane).
// ---------------------------------------------------------------------------
__global__ __launch_bounds__(256) void prep_kernel(
    const unsigned short* __restrict__ hraw,
    const void* __restrict__ Wqr, const void* __restrict__ bqr,
    const void* __restrict__ Wkr, const void* __restrict__ bkr,
    const void* __restrict__ Wvr, const void* __restrict__ bvr,
    int* __restrict__ gcursor, int* __restrict__ flag,
    unsigned short* __restrict__ Wfrag, float* __restrict__ bias_f)
{
    __shared__ int red[256];
    const int t   = threadIdx.x;
    const int tid = blockIdx.x * 256 + t;

    // --- per-block dtype probe (no cross-launch dependency) ---
    int cnt = 0;
    for (int i = t; i < 8192; i += 256) {
        unsigned short u = hraw[i];
        int e = (u >> 7) & 0xFF;
        if (e == 0xFF || e > 0x85 || (e == 0 && (u & 0x7F) != 0)) cnt++;
    }
    red[t] = cnt;
    __syncthreads();
    for (int s = 128; s > 0; s >>= 1) {
        if (t < s) red[t] += red[t + s];
        __syncthreads();
    }
    const bool f32 = (red[0] > 100);
    if (blockIdx.x == 0 && t == 0) *flag = red[0];   // for downstream kernels

    // --- zero gcursor (scatter reads it next launch) ---
    if (tid < SUBB_PAD) gcursor[tid] = 0;

    // --- bias vector ---
    if (tid < 384) {
        int mat = tid >> 7, c = tid & 127;
        const void* bp = (mat == 0) ? bqr : (mat == 1) ? bkr : bvr;
        bias_f[tid] = f32 ? ((const float*)bp)[c] : b2f(((const bf16*)bp)[c]);
    }

    // --- W fragment repack ---
    int l  = tid & 63;
    int s  = (tid >> 6) & 3;
    int nt = tid >> 8;
    int n  = nt * 16 + (l & 15);
    int k0 = s * 32 + (l >> 4) * 8;
    int mat = n >> 7, c = n & 127;
    const void* Wp = (mat == 0) ? Wqr : (mat == 1) ? Wkr : Wvr;

    unsigned short v[8];
#pragma unroll
    for (int j = 0; j < 8; ++j) {
        int k = k0 + j;
        float w = f32 ? ((const float*)Wp)[k * QKV_DIM + c]
                      : b2f(((const bf16*)Wp)[k * QKV_DIM + c]);
        v[j] = f2bf(w);
    }
    ushort4* o = (ushort4*)(Wfrag + (size_t)tid * 8);
    o[0] = make_ushort4(v[0], v[1], v[2], v[3]);
    o[1] = make_ushort4(v[4], v[5], v[6], v[7]);
}

// ---------------------------------------------------------------------------
// MFMA projection GEMM: [50000 x 128] @ [128 x 384].
// Qt: u16[row*128+c].  KVt 32-lane interleave (lane hl: uint4 = dims 4hl..4hl+3
// of K then V). Epilogue staged via LDS, coalesced uint4 copy-out.
// ---------------------------------------------------------------------------
__global__ __launch_bounds__(256) void gemm_kernel(
    const void* __restrict__ hraw,
    const unsigned short* __restrict__ Wfrag, const float* __restrict__ bias_f,
    const int* __restrict__ flag,
    unsigned short* __restrict__ Qt, unsigned short* __restrict__ KVt)
{
    __shared__ __align__(16) unsigned short smem[64 * OS_STRIDE];   // 50,176 B

    const bool f32 = (*flag > 100);
    const int m0  = blockIdx.x * 64;
    const int tid = threadIdx.x;

#pragma unroll
    for (int it = 0; it < 8; ++it) {
        int idx = it * 1024 + tid * 4;
        int r = idx >> 7, k = idx & 127;
        int row = m0 + r;
        ushort4 w4 = make_ushort4(0, 0, 0, 0);
        if (row < N_NODES) {
            if (f32) {
                float4 v4 = ((const float4*)hraw)[(size_t)row * 32 + (k >> 2)];
                w4 = make_ushort4(f2bf(v4.x), f2bf(v4.y), f2bf(v4.z), f2bf(v4.w));
            } else {
                uint2 u = ((const uint2*)hraw)[(size_t)row * 32 + (k >> 2)];
                w4 = make_ushort4((unsigned short)(u.x & 0xffffu), (unsigned short)(u.x >> 16),
                                  (unsigned short)(u.y & 0xffffu), (unsigned short)(u.y >> 16));
            }
        }
        *(ushort4*)&smem[r * HS_STRIDE + k] = w4;
    }
    __syncthreads();

    const int lane = tid & 63;
    const int wave = tid >> 6;
    const int qd   = lane >> 4;
    const int ln15 = lane & 15;

    bf16x8 afr[4][4];
#pragma unroll
    for (int ms = 0; ms < 4; ++ms)
#pragma unroll
        for (int s = 0; s < 4; ++s)
            afr[ms][s] = *(const bf16x8*)&smem[(ms * 16 + ln15) * HS_STRIDE + s * 32 + qd * 8];

    __syncthreads();   // smem reused for output staging

#pragma unroll
    for (int i = 0; i < 6; ++i) {
        const int nt  = wave + i * 4;
        const int col = nt * 16 + ln15;
        const float bs = bias_f[col];
        const int mat = col >> 7, c127 = col & 127;
        const int ocol = (mat == 0) ? c127
                       : 128 + 8 * (c127 >> 2) + (c127 & 3) + ((mat == 2) ? 4 : 0);

        bf16x8 bfr[4];
#pragma unroll
        for (int s = 0; s < 4; ++s)
            bfr[s] = *(const bf16x8*)(Wfrag + ((size_t)(nt * 4 + s) * 64 + lane) * 8);

#pragma unroll
        for (int ms = 0; ms < 4; ++ms) {
            f32x4 acc = {0.f, 0.f, 0.f, 0.f};
#pragma unroll
            for (int s = 0; s < 4; ++s)
                acc = __builtin_amdgcn_mfma_f32_16x16x32_bf16(afr[ms][s], bfr[s], acc, 0, 0, 0);
#pragma unroll
            for (int r = 0; r < 4; ++r) {
                int rl = ms * 16 + qd * 4 + r;
                smem[rl * OS_STRIDE + ocol] = f2bf(acc[r] + bs);
            }
        }
    }
    __syncthreads();

    for (int q = tid; q < 1024; q += 256) {
        int row = q >> 4, c = q & 15;
        int grow = m0 + row;
        if (grow < N_NODES)
            ((uint4*)Qt)[grow * 16 + c] = *(const uint4*)&smem[row * OS_STRIDE + c * 8];
    }
    for (int q = tid; q < 2048; q += 256) {
        int row = q >> 5, g = q & 31;
        int grow = m0 + row;
        if (grow < N_NODES)
            ((uint4*)KVt)[grow * 32 + g] = *(const uint4*)&smem[row * OS_STRIDE + 128 + g * 8];
    }
}

// ---------------------------------------------------------------------------
// Single-pass padded scatter: bucket sb = dst>>4 owns packed[sb*BCAP ...].
// packed = src (16b) | dst_local (4b) << 16.
// ---------------------------------------------------------------------------
__global__ __launch_bounds__(256) void scatter_kernel(const int* __restrict__ src,
                                                      const int* __restrict__ dst,
                                                      int* __restrict__ gcursor,
                                                      unsigned int* __restrict__ packed) {
    __shared__ int lcnt[SUBB];
    __shared__ int lbase[SUBB];
    int t = threadIdx.x;
    for (int i = t; i < SUBB; i += 256) lcnt[i] = 0;
    __syncthreads();
    int base = blockIdx.x * BH_CHUNK;
    for (int i = 0; i < 64; ++i) {
        int e = base + i * 256 + t;
        if (e < N_EDGES) atomicAdd(&lcnt[dst[e] >> 4], 1);
    }
    __syncthreads();
    for (int i = t; i < SUBB; i += 256) {
        int c = lcnt[i];
        lbase[i] = c ? atomicAdd(&gcursor[i], c) : 0;
        lcnt[i] = 0;
    }
    __syncthreads();
    for (int i = 0; i < 64; ++i) {
        int e = base + i * 256 + t;
        if (e < N_EDGES) {
            int d = dst[e];
            int b = d >> 4;
            int pos = lbase[b] + atomicAdd(&lcnt[b], 1);
            if (pos < BCAP)
                packed[b * BCAP + pos] = (unsigned int)src[e] | ((unsigned int)(d & 15) << 16);
        }
    }
}

// ---------------------------------------------------------------------------
// Fused bucket sort + gather aggregation (round-9 measured-best form).
// One block (256 thr) per 16-dst bucket; LDS counting sort; 4 waves x 4 dst.
// 2 edges per wave-instruction; 8-edge (4-pair) main loop.
// ---------------------------------------------------------------------------
__global__ __launch_bounds__(256) void bucket_agg_kernel(
    const unsigned short* __restrict__ Qt, const unsigned short* __restrict__ KVt,
    const unsigned int* __restrict__ packed, const int* __restrict__ gcursor,
    const int* __restrict__ flag, void* __restrict__ out)
{
    __shared__ unsigned int   lds_pk[BCAP];     // 4 KB
    __shared__ unsigned short lds_src[BCAP];    // 2 KB
    __shared__ int cnt16[16], base16[16], cur16[16];

    const int sb = blockIdx.x;
    const int t  = threadIdx.x;
    const int nb = min(gcursor[sb], BCAP);

    if (t < 16) { cnt16[t] = 0; cur16[t] = 0; }
    __syncthreads();

    for (int j = t; j < nb; j += 256) {
        unsigned int pk = packed[sb * BCAP + j];
        lds_pk[j] = pk;
        atomicAdd(&cnt16[(pk >> 16) & 15], 1);
    }
    __syncthreads();
    if (t == 0) {
        int acc = 0;
#pragma unroll
        for (int i = 0; i < 16; ++i) { base16[i] = acc; acc += cnt16[i]; }
    }
    __syncthreads();
    for (int j = t; j < nb; j += 256) {
        unsigned int pk = lds_pk[j];
        int dl = (pk >> 16) & 15;
        int pos = base16[dl] + atomicAdd(&cur16[dl], 1);
        lds_src[pos] = (unsigned short)(pk & 0xffffu);
    }
    __syncthreads();

    const int wave = t >> 6;
    const int lane = t & 63;
    const int half = lane >> 5;            // 0 = even edge, 1 = odd edge
    const int hl   = lane & 31;            // dims 4hl..4hl+3
    const uint4* KV4 = (const uint4*)KVt;  // [row*32 + hl]
    const bool of32 = (*flag > 100);

    for (int dl = wave; dl < 16; dl += 4) {
        const int d = sb * 16 + dl;
        uint2 qw = ((const uint2*)Qt)[d * 32 + hl];
        const float q0 = u16tof(qw.x & 0xffffu), q1 = u16tof(qw.x >> 16);
        const float q2 = u16tof(qw.y & 0xffffu), q3 = u16tof(qw.y >> 16);
        const int off = base16[dl];
        const int n   = cnt16[dl];

        float a0 = 0.f, a1 = 0.f, a2 = 0.f, a3 = 0.f, zz = 0.f;

#define CONSUME(KV, SCMASK)                                                     \
        {                                                                       \
            float p = fmaf(u16tof((KV).x & 0xffffu), q0,                        \
                      fmaf(u16tof((KV).x >> 16), q1,                            \
                      fmaf(u16tof((KV).y & 0xffffu), q2,                        \
                           u16tof((KV).y >> 16) * q3)));                        \
            p += __shfl_xor(p, 1);                                              \
            p += __shfl_xor(p, 2);                                              \
            float sc = __expf(__builtin_amdgcn_fmed3f(p * 0.25f, -5.f, 5.f));   \
            sc *= (SCMASK);                                                     \
            a0 = fmaf(u16tof((KV).z & 0xffffu), sc, a0);                        \
            a1 = fmaf(u16tof((KV).z >> 16),     sc, a1);                        \
            a2 = fmaf(u16tof((KV).w & 0xffffu), sc, a2);                        \
            a3 = fmaf(u16tof((KV).w >> 16),     sc, a3);                        \
            zz += sc;                                                           \
        }

        int j = 0;
        for (; j + 8 <= n; j += 8) {       // 4 pairs = 8 edges, 4 loads in flight
            int e[4];
#pragma unroll
            for (int u = 0; u < 4; ++u) e[u] = lds_src[off + j + 2 * u + half];
            uint4 kv[4];
#pragma unroll
            for (int u = 0; u < 4; ++u) kv[u] = KV4[e[u] * 32 + hl];
#pragma unroll
            for (int u = 0; u < 4; ++u) CONSUME(kv[u], 1.f)
        }
        for (; j + 2 <= n; j += 2) {       // single pair
            int e = lds_src[off + j + half];
            uint4 kv = KV4[e * 32 + hl];
            CONSUME(kv, 1.f)
        }
        if (j < n) {                       // odd leftover: lower half only
            int e = lds_src[off + j];
            uint4 kv = KV4[e * 32 + hl];
            CONSUME(kv, (half == 0) ? 1.f : 0.f)
        }
#undef CONSUME

        a0 += __shfl_xor(a0, 32);
        a1 += __shfl_xor(a1, 32);
        a2 += __shfl_xor(a2, 32);
        a3 += __shfl_xor(a3, 32);
        zz += __shfl_xor(zz, 32);

        const float inv = 1.f / (zz + 1e-6f);
        const float r0 = a0 * inv, r1 = a1 * inv, r2 = a2 * inv, r3 = a3 * inv;

        if (half == 0) {
            if (of32) {
                ((float4*)out)[d * 32 + hl] = make_float4(r0, r1, r2, r3);
            } else {
                unsigned int w0 = ((unsigned int)f2bf(r1) << 16) | f2bf(r0);
                unsigned int w1 = ((unsigned int)f2bf(r3) << 16) | f2bf(r2);
                ((uint2*)out)[d * 32 + hl] = make_uint2(w0, w1);
            }
        }
    }
}

// ---------------------------------------------------------------------------
extern "C" void kernel_launch(void* const* d_in, const int* in_sizes, int n_in,
                              void* d_out, int out_size, void* d_ws, size_t ws_size,
                              hipStream_t stream)
{
    const void* h  = d_in[0];
    const void* Wq = d_in[1];
    const void* bq = d_in[2];
    const void* Wk = d_in[3];
    const void* bk = d_in[4];
    const void* Wv = d_in[5];
    const void* bv = d_in[6];
    const int*  src = (const int*)d_in[7];
    const int*  dst = (const int*)d_in[8];

    const size_t NQ = (size_t)N_NODES * QKV_DIM;   // 6,400,000
    const size_t WFRAG_N = 24 * 4 * 64 * 8;        // 49,152

    // ws layout:
    //  [Qt u16 NQ][KVt u16 2*NQ]                        38.4 MB
    //  [Wfrag u16 WFRAG_N][bias_f f32 384]
    //  [gcursor int SUBB_PAD][flag int 16]
    //  [packed u32 SUBB*BCAP]                           12.8 MB
    const size_t need = 3 * NQ * 2 + WFRAG_N * 2 + 384 * 4
                      + ((size_t)SUBB_PAD + 16) * sizeof(int)
                      + (size_t)SUBB * BCAP * 4;

    if (ws_size < need) {
        sentinel_kernel<<<(out_size + 255) / 256, 256, 0, stream>>>((unsigned short*)d_out, out_size);
        return;
    }

    unsigned short* Qt  = (unsigned short*)d_ws;
    unsigned short* KVt = Qt + NQ;
    unsigned short* Wfrag = KVt + 2 * NQ;
    float* bias_f = (float*)(Wfrag + WFRAG_N);
    int* gcursor = (int*)(bias_f + 384);
    int* flag    = gcursor + SUBB_PAD;
    unsigned int* packed = (unsigned int*)(flag + 16);

    prep_kernel<<<24, 256, 0, stream>>>((const unsigned short*)h,
        Wq, bq, Wk, bk, Wv, bv, gcursor, flag, Wfrag, bias_f);

    const int gemm_blocks = (N_NODES + 63) / 64;               // 782
    gemm_kernel<<<gemm_blocks, 256, 0, stream>>>(h, Wfrag, bias_f, flag, Qt, KVt);

    scatter_kernel<<<BH_BLOCKS, 256, 0, stream>>>(src, dst, gcursor, packed);

    bucket_agg_kernel<<<SUBB, 256, 0, stream>>>(Qt, KVt, packed, gcursor, flag, d_out);
}

// Round 13
// 279.903 us; speedup vs baseline: 1.0954x; 1.0453x over previous
//
#include <hip/hip_runtime.h>
#include <hip/hip_bf16.h>
#include <cstddef>

#define N_NODES 50000
#define N_EDGES 1600000
#define IN_DIM 128
#define OUT_DIM 16
#define N_HEADS 8
#define QKV_DIM 128               // N_HEADS * OUT_DIM
#define HS_STRIDE 136             // padded LDS row stride for h staging (u16)
#define OS_STRIDE 392             // padded LDS row stride for out staging (u16)

#define SUBB 3125                 // N_NODES/16 sub-buckets (16 dst nodes each)
#define BCAP 1024                 // LDS staging cap per bucket (lambda=512, >20 sigma)
#define BH_CHUNK 8192             // edges per scatter block
#define BH_BLOCKS 196             // 196*8192 = 1,605,632 >= 1.6M

typedef __hip_bfloat16 bf16;
typedef short bf16x8 __attribute__((ext_vector_type(8)));
typedef float f32x4  __attribute__((ext_vector_type(4)));

__device__ __forceinline__ float b2f(bf16 x) { return __bfloat162float(x); }

__device__ __forceinline__ float u16tof(unsigned int u) {
    unsigned int x = u << 16;
    float f;
    __builtin_memcpy(&f, &x, 4);
    return f;
}

__device__ __forceinline__ unsigned short f2bf(float v) {
    bf16 b = __float2bfloat16(v);
    unsigned short u;
    __builtin_memcpy(&u, &b, 2);
    return u;
}

__global__ __launch_bounds__(256) void sentinel_kernel(unsigned short* __restrict__ out, int n) {
    int i = blockIdx.x * 256 + threadIdx.x;
    if (i < n) out[i] = 0x42C8;
}

// ---------------------------------------------------------------------------
// prep: self-probe input dtype (bf16-impossible bit patterns in first 8192
// u16 of h; fp32 -> ~1960 hits, bf16 -> 0), publish flag, then repack
// Wq|Wk|Wv into MFMA B-fragment order + fp32 bias vector.
// ---------------------------------------------------------------------------
__global__ __launch_bounds__(256) void prep_kernel(
    const unsigned short* __restrict__ hraw,
    const void* __restrict__ Wqr, const void* __restrict__ bqr,
    const void* __restrict__ Wkr, const void* __restrict__ bkr,
    const void* __restrict__ Wvr, const void* __restrict__ bvr,
    int* __restrict__ flag,
    unsigned short* __restrict__ Wfrag, float* __restrict__ bias_f)
{
    __shared__ int red[256];
    const int t   = threadIdx.x;
    const int tid = blockIdx.x * 256 + t;

    int cnt = 0;
    for (int i = t; i < 8192; i += 256) {
        unsigned short u = hraw[i];
        int e = (u >> 7) & 0xFF;
        if (e == 0xFF || e > 0x85 || (e == 0 && (u & 0x7F) != 0)) cnt++;
    }
    red[t] = cnt;
    __syncthreads();
    for (int s = 128; s > 0; s >>= 1) {
        if (t < s) red[t] += red[t + s];
        __syncthreads();
    }
    const bool f32 = (red[0] > 100);
    if (blockIdx.x == 0 && t == 0) *flag = red[0];

    if (tid < 384) {
        int mat = tid >> 7, c = tid & 127;
        const void* bp = (mat == 0) ? bqr : (mat == 1) ? bkr : bvr;
        bias_f[tid] = f32 ? ((const float*)bp)[c] : b2f(((const bf16*)bp)[c]);
    }

    int l  = tid & 63;
    int s  = (tid >> 6) & 3;
    int nt = tid >> 8;
    int n  = nt * 16 + (l & 15);
    int k0 = s * 32 + (l >> 4) * 8;
    int mat = n >> 7, c = n & 127;
    const void* Wp = (mat == 0) ? Wqr : (mat == 1) ? Wkr : Wvr;

    unsigned short v[8];
#pragma unroll
    for (int j = 0; j < 8; ++j) {
        int k = k0 + j;
        float w = f32 ? ((const float*)Wp)[k * QKV_DIM + c]
                      : b2f(((const bf16*)Wp)[k * QKV_DIM + c]);
        v[j] = f2bf(w);
    }
    ushort4* o = (ushort4*)(Wfrag + (size_t)tid * 8);
    o[0] = make_ushort4(v[0], v[1], v[2], v[3]);
    o[1] = make_ushort4(v[4], v[5], v[6], v[7]);
}

// ---------------------------------------------------------------------------
// MFMA projection GEMM: [50000 x 128] @ [128 x 384].
// Qt: u16[row*128+c].  KVt 32-lane interleave (lane hl: uint4 = dims 4hl..4hl+3
// of K then V). Epilogue staged via LDS, coalesced uint4 copy-out.
// ---------------------------------------------------------------------------
__global__ __launch_bounds__(256) void gemm_kernel(
    const void* __restrict__ hraw,
    const unsigned short* __restrict__ Wfrag, const float* __restrict__ bias_f,
    const int* __restrict__ flag,
    unsigned short* __restrict__ Qt, unsigned short* __restrict__ KVt)
{
    __shared__ __align__(16) unsigned short smem[64 * OS_STRIDE];   // 50,176 B

    const bool f32 = (*flag > 100);
    const int m0  = blockIdx.x * 64;
    const int tid = threadIdx.x;

#pragma unroll
    for (int it = 0; it < 8; ++it) {
        int idx = it * 1024 + tid * 4;
        int r = idx >> 7, k = idx & 127;
        int row = m0 + r;
        ushort4 w4 = make_ushort4(0, 0, 0, 0);
        if (row < N_NODES) {
            if (f32) {
                float4 v4 = ((const float4*)hraw)[(size_t)row * 32 + (k >> 2)];
                w4 = make_ushort4(f2bf(v4.x), f2bf(v4.y), f2bf(v4.z), f2bf(v4.w));
            } else {
                uint2 u = ((const uint2*)hraw)[(size_t)row * 32 + (k >> 2)];
                w4 = make_ushort4((unsigned short)(u.x & 0xffffu), (unsigned short)(u.x >> 16),
                                  (unsigned short)(u.y & 0xffffu), (unsigned short)(u.y >> 16));
            }
        }
        *(ushort4*)&smem[r * HS_STRIDE + k] = w4;
    }
    __syncthreads();

    const int lane = tid & 63;
    const int wave = tid >> 6;
    const int qd   = lane >> 4;
    const int ln15 = lane & 15;

    bf16x8 afr[4][4];
#pragma unroll
    for (int ms = 0; ms < 4; ++ms)
#pragma unroll
        for (int s = 0; s < 4; ++s)
            afr[ms][s] = *(const bf16x8*)&smem[(ms * 16 + ln15) * HS_STRIDE + s * 32 + qd * 8];

    __syncthreads();   // smem reused for output staging

#pragma unroll
    for (int i = 0; i < 6; ++i) {
        const int nt  = wave + i * 4;
        const int col = nt * 16 + ln15;
        const float bs = bias_f[col];
        const int mat = col >> 7, c127 = col & 127;
        const int ocol = (mat == 0) ? c127
                       : 128 + 8 * (c127 >> 2) + (c127 & 3) + ((mat == 2) ? 4 : 0);

        bf16x8 bfr[4];
#pragma unroll
        for (int s = 0; s < 4; ++s)
            bfr[s] = *(const bf16x8*)(Wfrag + ((size_t)(nt * 4 + s) * 64 + lane) * 8);

#pragma unroll
        for (int ms = 0; ms < 4; ++ms) {
            f32x4 acc = {0.f, 0.f, 0.f, 0.f};
#pragma unroll
            for (int s = 0; s < 4; ++s)
                acc = __builtin_amdgcn_mfma_f32_16x16x32_bf16(afr[ms][s], bfr[s], acc, 0, 0, 0);
#pragma unroll
            for (int r = 0; r < 4; ++r) {
                int rl = ms * 16 + qd * 4 + r;
                smem[rl * OS_STRIDE + ocol] = f2bf(acc[r] + bs);
            }
        }
    }
    __syncthreads();

    for (int q = tid; q < 1024; q += 256) {
        int row = q >> 4, c = q & 15;
        int grow = m0 + row;
        if (grow < N_NODES)
            ((uint4*)Qt)[grow * 16 + c] = *(const uint4*)&smem[row * OS_STRIDE + c * 8];
    }
    for (int q = tid; q < 2048; q += 256) {
        int row = q >> 5, g = q & 31;
        int grow = m0 + row;
        if (grow < N_NODES)
            ((uint4*)KVt)[grow * 32 + g] = *(const uint4*)&smem[row * OS_STRIDE + 128 + g * 8];
    }
}

// ---------------------------------------------------------------------------
// Dense LDS bucket-sort scatter: block b owns edges [b*8192, b*8192+8192) AND
// output region packed[b*8192 ...]. Sorts its chunk by bucket (dst>>4) fully
// in LDS, writes out coalesced, and emits offcnt[b][sb] = off<<16 | cnt.
// NO global atomics anywhere.
// ---------------------------------------------------------------------------
__global__ __launch_bounds__(256) void scatter_kernel(
    const int* __restrict__ src, const int* __restrict__ dst,
    unsigned int* __restrict__ packed, unsigned int* __restrict__ offcnt)
{
    __shared__ int lcnt[SUBB];                  // 12.5 KB
    __shared__ int loff[SUBB];                  // 12.5 KB
    __shared__ unsigned int stage[BH_CHUNK];    // 32 KB
    __shared__ int sm[256];
    __shared__ int carry;

    const int t    = threadIdx.x;
    const int base = blockIdx.x * BH_CHUNK;
    const int nb   = min(N_EDGES - base, BH_CHUNK);

    for (int i = t; i < SUBB; i += 256) lcnt[i] = 0;
    if (t == 0) carry = 0;
    __syncthreads();

    // pass 1: count buckets
    for (int i = t; i < nb; i += 256)
        atomicAdd(&lcnt[dst[base + i] >> 4], 1);
    __syncthreads();

    // exclusive scan of lcnt -> loff (13 chunks of 256, Hillis-Steele + carry)
    for (int c = 0; c < 13; ++c) {
        int i = c * 256 + t;
        int x = (i < SUBB) ? lcnt[i] : 0;
        int v = x;
        sm[t] = v;
        __syncthreads();
        for (int s = 1; s < 256; s <<= 1) {
            int a = (t >= s) ? sm[t - s] : 0;
            __syncthreads();
            v += a;
            sm[t] = v;
            __syncthreads();
        }
        if (i < SUBB) loff[i] = carry + v - x;
        __syncthreads();
        if (t == 255) carry += v;
        __syncthreads();
    }

    // emit offcnt (dense, block-major), then reuse lcnt as cursors
    for (int i = t; i < SUBB; i += 256)
        offcnt[(size_t)blockIdx.x * SUBB + i] =
            ((unsigned int)loff[i] << 16) | (unsigned int)lcnt[i];
    __syncthreads();
    for (int i = t; i < SUBB; i += 256) lcnt[i] = 0;
    __syncthreads();

    // pass 2: reposition into LDS stage
    for (int i = t; i < nb; i += 256) {
        int d = dst[base + i];
        int b = d >> 4;
        int pos = loff[b] + atomicAdd(&lcnt[b], 1);
        stage[pos] = (unsigned int)src[base + i] | ((unsigned int)(d & 15) << 16);
    }
    __syncthreads();

    // pass 3: coalesced write-out
    for (int i = t; i < nb; i += 256)
        packed[base + i] = stage[i];
}

// ---------------------------------------------------------------------------
// Fused run-gather + bucket sort + aggregation. One block per 16-dst bucket.
// Prologue pulls the bucket's 196 runs (offcnt table) into LDS; then LDS
// counting sort; then 4 waves x 4 dst, 2 edges per wave-instruction.
// ---------------------------------------------------------------------------
__global__ __launch_bounds__(256) void bucket_agg_kernel(
    const unsigned short* __restrict__ Qt, const unsigned short* __restrict__ KVt,
    const unsigned int* __restrict__ packed, const unsigned int* __restrict__ offcnt,
    const int* __restrict__ flag, void* __restrict__ out)
{
    __shared__ unsigned int   lds_pk[BCAP];     // 4 KB (also scan scratch)
    __shared__ unsigned short lds_src[BCAP];    // 2 KB
    __shared__ int runoff[BH_BLOCKS], runcnt[BH_BLOCKS], runpfx[BH_BLOCKS];
    __shared__ int cnt16[16], base16[16], cur16[16];
    __shared__ int nb_s;

    const int sb = blockIdx.x;
    const int t  = threadIdx.x;

    if (t < 16) { cnt16[t] = 0; cur16[t] = 0; }
    if (t < BH_BLOCKS) {
        unsigned int oc = offcnt[(size_t)t * SUBB + sb];
        runoff[t] = t * BH_CHUNK + (int)(oc >> 16);
        runcnt[t] = (int)(oc & 0xffffu);
    }
    __syncthreads();

    // scan 196 run counts (Hillis-Steele over 256 via lds_pk scratch)
    {
        int* sm = (int*)lds_pk;
        int x = (t < BH_BLOCKS) ? runcnt[t] : 0;
        int v = x;
        sm[t] = v;
        __syncthreads();
        for (int s = 1; s < 256; s <<= 1) {
            int a = (t >= s) ? sm[t - s] : 0;
            __syncthreads();
            v += a;
            sm[t] = v;
            __syncthreads();
        }
        if (t < BH_BLOCKS) runpfx[t] = v - x;
        if (t == 255) nb_s = v;
        __syncthreads();
    }
    const int nb = min(nb_s, BCAP);

    // gather runs into lds_pk, counting heads on the fly
    for (int r = t; r < BH_BLOCKS; r += 256) {
        int ro = runoff[r], rc = runcnt[r], rp = runpfx[r];
        for (int j = 0; j < rc; ++j) {
            int dpos = rp + j;
            if (dpos < BCAP) {
                unsigned int pk = packed[ro + j];
                lds_pk[dpos] = pk;
                atomicAdd(&cnt16[(pk >> 16) & 15], 1);
            }
        }
    }
    __syncthreads();
    if (t == 0) {
        int acc = 0;
#pragma unroll
        for (int i = 0; i < 16; ++i) { base16[i] = acc; acc += cnt16[i]; }
    }
    __syncthreads();
    for (int j = t; j < nb; j += 256) {
        unsigned int pk = lds_pk[j];
        int dl = (pk >> 16) & 15;
        int pos = base16[dl] + atomicAdd(&cur16[dl], 1);
        lds_src[pos] = (unsigned short)(pk & 0xffffu);
    }
    __syncthreads();

    const int wave = t >> 6;
    const int lane = t & 63;
    const int half = lane >> 5;            // 0 = even edge, 1 = odd edge
    const int hl   = lane & 31;            // dims 4hl..4hl+3
    const uint4* KV4 = (const uint4*)KVt;  // [row*32 + hl]
    const bool of32 = (*flag > 100);

    for (int dl = wave; dl < 16; dl += 4) {
        const int d = sb * 16 + dl;
        uint2 qw = ((const uint2*)Qt)[d * 32 + hl];
        const float q0 = u16tof(qw.x & 0xffffu), q1 = u16tof(qw.x >> 16);
        const float q2 = u16tof(qw.y & 0xffffu), q3 = u16tof(qw.y >> 16);
        const int off = base16[dl];
        const int n   = cnt16[dl];

        float a0 = 0.f, a1 = 0.f, a2 = 0.f, a3 = 0.f, zz = 0.f;

#define CONSUME(KV, SCMASK)                                                     \
        {                                                                       \
            float p = fmaf(u16tof((KV).x & 0xffffu), q0,                        \
                      fmaf(u16tof((KV).x >> 16), q1,                            \
                      fmaf(u16tof((KV).y & 0xffffu), q2,                        \
                           u16tof((KV).y >> 16) * q3)));                        \
            p += __shfl_xor(p, 1);                                              \
            p += __shfl_xor(p, 2);                                              \
            float sc = __expf(__builtin_amdgcn_fmed3f(p * 0.25f, -5.f, 5.f));   \
            sc *= (SCMASK);                                                     \
            a0 = fmaf(u16tof((KV).z & 0xffffu), sc, a0);                        \
            a1 = fmaf(u16tof((KV).z >> 16),     sc, a1);                        \
            a2 = fmaf(u16tof((KV).w & 0xffffu), sc, a2);                        \
            a3 = fmaf(u16tof((KV).w >> 16),     sc, a3);                        \
            zz += sc;                                                           \
        }

        int j = 0;
        for (; j + 8 <= n; j += 8) {       // 4 pairs = 8 edges, 4 loads in flight
            int e[4];
#pragma unroll
            for (int u = 0; u < 4; ++u) e[u] = lds_src[off + j + 2 * u + half];
            uint4 kv[4];
#pragma unroll
            for (int u = 0; u < 4; ++u) kv[u] = KV4[e[u] * 32 + hl];
#pragma unroll
            for (int u = 0; u < 4; ++u) CONSUME(kv[u], 1.f)
        }
        for (; j + 2 <= n; j += 2) {       // single pair
            int e = lds_src[off + j + half];
            uint4 kv = KV4[e * 32 + hl];
            CONSUME(kv, 1.f)
        }
        if (j < n) {                       // odd leftover: lower half only
            int e = lds_src[off + j];
            uint4 kv = KV4[e * 32 + hl];
            CONSUME(kv, (half == 0) ? 1.f : 0.f)
        }
#undef CONSUME

        a0 += __shfl_xor(a0, 32);
        a1 += __shfl_xor(a1, 32);
        a2 += __shfl_xor(a2, 32);
        a3 += __shfl_xor(a3, 32);
        zz += __shfl_xor(zz, 32);

        const float inv = 1.f / (zz + 1e-6f);
        const float r0 = a0 * inv, r1 = a1 * inv, r2 = a2 * inv, r3 = a3 * inv;

        if (half == 0) {
            if (of32) {
                ((float4*)out)[d * 32 + hl] = make_float4(r0, r1, r2, r3);
            } else {
                unsigned int w0 = ((unsigned int)f2bf(r1) << 16) | f2bf(r0);
                unsigned int w1 = ((unsigned int)f2bf(r3) << 16) | f2bf(r2);
                ((uint2*)out)[d * 32 + hl] = make_uint2(w0, w1);
            }
        }
    }
}

// ---------------------------------------------------------------------------
extern "C" void kernel_launch(void* const* d_in, const int* in_sizes, int n_in,
                              void* d_out, int out_size, void* d_ws, size_t ws_size,
                              hipStream_t stream)
{
    const void* h  = d_in[0];
    const void* Wq = d_in[1];
    const void* bq = d_in[2];
    const void* Wk = d_in[3];
    const void* bk = d_in[4];
    const void* Wv = d_in[5];
    const void* bv = d_in[6];
    const int*  src = (const int*)d_in[7];
    const int*  dst = (const int*)d_in[8];

    const size_t NQ = (size_t)N_NODES * QKV_DIM;   // 6,400,000
    const size_t WFRAG_N = 24 * 4 * 64 * 8;        // 49,152
    const size_t PACKED_N = (size_t)BH_BLOCKS * BH_CHUNK;   // 1,605,632
    const size_t OFFCNT_N = (size_t)BH_BLOCKS * SUBB;       // 612,500

    // ws layout:
    //  [Qt u16 NQ][KVt u16 2*NQ]                        38.4 MB
    //  [Wfrag u16 WFRAG_N][bias_f f32 384][flag int 16]
    //  [packed u32 PACKED_N]                            6.4 MB
    //  [offcnt u32 OFFCNT_N]                            2.45 MB
    const size_t need = 3 * NQ * 2 + WFRAG_N * 2 + 384 * 4 + 64
                      + PACKED_N * 4 + OFFCNT_N * 4;

    if (ws_size < need) {
        sentinel_kernel<<<(out_size + 255) / 256, 256, 0, stream>>>((unsigned short*)d_out, out_size);
        return;
    }

    unsigned short* Qt  = (unsigned short*)d_ws;
    unsigned short* KVt = Qt + NQ;
    unsigned short* Wfrag = KVt + 2 * NQ;
    float* bias_f = (float*)(Wfrag + WFRAG_N);
    int* flag     = (int*)(bias_f + 384);
    unsigned int* packed = (unsigned int*)(flag + 16);
    unsigned int* offcnt = packed + PACKED_N;

    prep_kernel<<<24, 256, 0, stream>>>((const unsigned short*)h,
        Wq, bq, Wk, bk, Wv, bv, flag, Wfrag, bias_f);

    const int gemm_blocks = (N_NODES + 63) / 64;               // 782
    gemm_kernel<<<gemm_blocks, 256, 0, stream>>>(h, Wfrag, bias_f, flag, Qt, KVt);

    scatter_kernel<<<BH_BLOCKS, 256, 0, stream>>>(src, dst, packed, offcnt);

    bucket_agg_kernel<<<SUBB, 256, 0, stream>>>(Qt, KVt, packed, offcnt, flag, d_out);
}

// Round 14
// 265.374 us; speedup vs baseline: 1.1553x; 1.0547x over previous
//
#include <hip/hip_runtime.h>
#include <hip/hip_bf16.h>
#include <cstddef>

#define N_NODES 50000
#define N_EDGES 1600000
#define IN_DIM 128
#define OUT_DIM 16
#define N_HEADS 8
#define QKV_DIM 128               // N_HEADS * OUT_DIM
#define HS_STRIDE 136             // padded LDS row stride for h staging (u16)
#define OS_STRIDE 392             // padded LDS row stride for out staging (u16)

#define SUBB 3125                 // N_NODES/16 sub-buckets (16 dst nodes each)
#define BCAP 1024                 // LDS staging cap per bucket (lambda=512, >20 sigma)
#define BH_CHUNK 8192             // edges per scatter block
#define BH_BLOCKS 196             // 196*8192 = 1,605,632 >= 1.6M
#define GEMM_BLOCKS 782           // ceil(50000/64)
#define FUSED_BLOCKS (BH_BLOCKS + GEMM_BLOCKS)

typedef __hip_bfloat16 bf16;
typedef short bf16x8 __attribute__((ext_vector_type(8)));
typedef float f32x4  __attribute__((ext_vector_type(4)));

__device__ __forceinline__ float b2f(bf16 x) { return __bfloat162float(x); }

__device__ __forceinline__ float u16tof(unsigned int u) {
    unsigned int x = u << 16;
    float f;
    __builtin_memcpy(&f, &x, 4);
    return f;
}

__device__ __forceinline__ unsigned short f2bf(float v) {
    bf16 b = __float2bfloat16(v);
    unsigned short u;
    __builtin_memcpy(&u, &b, 2);
    return u;
}

__global__ __launch_bounds__(256) void sentinel_kernel(unsigned short* __restrict__ out, int n) {
    int i = blockIdx.x * 256 + threadIdx.x;
    if (i < n) out[i] = 0x42C8;
}

// ---------------------------------------------------------------------------
// prep: self-probe input dtype, publish flag, repack Wq|Wk|Wv into MFMA
// B-fragment order + fp32 bias vector. (byte-identical to R13)
// ---------------------------------------------------------------------------
__global__ __launch_bounds__(256) void prep_kernel(
    const unsigned short* __restrict__ hraw,
    const void* __restrict__ Wqr, const void* __restrict__ bqr,
    const void* __restrict__ Wkr, const void* __restrict__ bkr,
    const void* __restrict__ Wvr, const void* __restrict__ bvr,
    int* __restrict__ flag,
    unsigned short* __restrict__ Wfrag, float* __restrict__ bias_f)
{
    __shared__ int red[256];
    const int t   = threadIdx.x;
    const int tid = blockIdx.x * 256 + t;

    int cnt = 0;
    for (int i = t; i < 8192; i += 256) {
        unsigned short u = hraw[i];
        int e = (u >> 7) & 0xFF;
        if (e == 0xFF || e > 0x85 || (e == 0 && (u & 0x7F) != 0)) cnt++;
    }
    red[t] = cnt;
    __syncthreads();
    for (int s = 128; s > 0; s >>= 1) {
        if (t < s) red[t] += red[t + s];
        __syncthreads();
    }
    const bool f32 = (red[0] > 100);
    if (blockIdx.x == 0 && t == 0) *flag = red[0];

    if (tid < 384) {
        int mat = tid >> 7, c = tid & 127;
        const void* bp = (mat == 0) ? bqr : (mat == 1) ? bkr : bvr;
        bias_f[tid] = f32 ? ((const float*)bp)[c] : b2f(((const bf16*)bp)[c]);
    }

    int l  = tid & 63;
    int s  = (tid >> 6) & 3;
    int nt = tid >> 8;
    int n  = nt * 16 + (l & 15);
    int k0 = s * 32 + (l >> 4) * 8;
    int mat = n >> 7, c = n & 127;
    const void* Wp = (mat == 0) ? Wqr : (mat == 1) ? Wkr : Wvr;

    unsigned short v[8];
#pragma unroll
    for (int j = 0; j < 8; ++j) {
        int k = k0 + j;
        float w = f32 ? ((const float*)Wp)[k * QKV_DIM + c]
                      : b2f(((const bf16*)Wp)[k * QKV_DIM + c]);
        v[j] = f2bf(w);
    }
    ushort4* o = (ushort4*)(Wfrag + (size_t)tid * 8);
    o[0] = make_ushort4(v[0], v[1], v[2], v[3]);
    o[1] = make_ushort4(v[4], v[5], v[6], v[7]);
}

// ---------------------------------------------------------------------------
// FUSED kernel: blocks [0,196) = dense LDS bucket-sort scatter;
//               blocks [196,978) = MFMA projection GEMM.
// The two jobs are independent; fusing overlaps scatter's undersubscribed,
// barrier-heavy blocks with gemm's streaming blocks, and exposes the
// combined true duration to rocprof.
// LDS: one 50,176 B arena reinterpreted per branch (scatter uses 46.3 KB:
// cursor array seeded with scanned offsets replaces the old loff[]).
// ---------------------------------------------------------------------------
__global__ __launch_bounds__(256) void fused_gs_kernel(
    const void* __restrict__ hraw,
    const unsigned short* __restrict__ Wfrag, const float* __restrict__ bias_f,
    const int* __restrict__ flag,
    unsigned short* __restrict__ Qt, unsigned short* __restrict__ KVt,
    const int* __restrict__ src, const int* __restrict__ dst,
    unsigned int* __restrict__ packed, unsigned int* __restrict__ offcnt)
{
    __shared__ __align__(16) unsigned char arena[64 * OS_STRIDE * 2];   // 50,176 B
    const int t = threadIdx.x;

    if (blockIdx.x < BH_BLOCKS) {
        // ----------------- scatter branch -----------------
        int* lcnt           = (int*)arena;                        // 12,500 B
        unsigned int* stage = (unsigned int*)(arena + 12544);     // 32,768 B
        int* sm             = (int*)(arena + 45312);              //  1,024 B
        int* carryp         = (int*)(arena + 46336);

        const int b    = blockIdx.x;
        const int base = b * BH_CHUNK;
        const int nb   = min(N_EDGES - base, BH_CHUNK);

        for (int i = t; i < SUBB; i += 256) lcnt[i] = 0;
        if (t == 0) *carryp = 0;
        __syncthreads();

        // pass 1: count buckets
        for (int i = t; i < nb; i += 256)
            atomicAdd(&lcnt[dst[base + i] >> 4], 1);
        __syncthreads();

        // scan; emit offcnt; seed lcnt with offsets (cursor = absolute pos)
        for (int c = 0; c < 13; ++c) {
            int i = c * 256 + t;
            int x = (i < SUBB) ? lcnt[i] : 0;
            int v = x;
            sm[t] = v;
            __syncthreads();
            for (int s = 1; s < 256; s <<= 1) {
                int a = (t >= s) ? sm[t - s] : 0;
                __syncthreads();
                v += a;
                sm[t] = v;
                __syncthreads();
            }
            int off = *carryp + v - x;
            if (i < SUBB) {
                offcnt[(size_t)b * SUBB + i] =
                    ((unsigned int)off << 16) | (unsigned int)x;
                lcnt[i] = off;             // cursor seeded with offset
            }
            __syncthreads();
            if (t == 255) *carryp += v;
            __syncthreads();
        }

        // pass 2: reposition into LDS stage (cursor gives absolute pos)
        for (int i = t; i < nb; i += 256) {
            int d = dst[base + i];
            int bk = d >> 4;
            int pos = atomicAdd(&lcnt[bk], 1);
            stage[pos] = (unsigned int)src[base + i] | ((unsigned int)(d & 15) << 16);
        }
        __syncthreads();

        // pass 3: coalesced write-out
        for (int i = t; i < nb; i += 256)
            packed[base + i] = stage[i];

    } else {
        // ----------------- gemm branch -----------------
        unsigned short* smem = (unsigned short*)arena;

        const bool f32 = (*flag > 100);
        const int m0 = (blockIdx.x - BH_BLOCKS) * 64;

#pragma unroll
        for (int it = 0; it < 8; ++it) {
            int idx = it * 1024 + t * 4;
            int r = idx >> 7, k = idx & 127;
            int row = m0 + r;
            ushort4 w4 = make_ushort4(0, 0, 0, 0);
            if (row < N_NODES) {
                if (f32) {
                    float4 v4 = ((const float4*)hraw)[(size_t)row * 32 + (k >> 2)];
                    w4 = make_ushort4(f2bf(v4.x), f2bf(v4.y), f2bf(v4.z), f2bf(v4.w));
                } else {
                    uint2 u = ((const uint2*)hraw)[(size_t)row * 32 + (k >> 2)];
                    w4 = make_ushort4((unsigned short)(u.x & 0xffffu), (unsigned short)(u.x >> 16),
                                      (unsigned short)(u.y & 0xffffu), (unsigned short)(u.y >> 16));
                }
            }
            *(ushort4*)&smem[r * HS_STRIDE + k] = w4;
        }
        __syncthreads();

        const int lane = t & 63;
        const int wave = t >> 6;
        const int qd   = lane >> 4;
        const int ln15 = lane & 15;

        bf16x8 afr[4][4];
#pragma unroll
        for (int ms = 0; ms < 4; ++ms)
#pragma unroll
            for (int s = 0; s < 4; ++s)
                afr[ms][s] = *(const bf16x8*)&smem[(ms * 16 + ln15) * HS_STRIDE + s * 32 + qd * 8];

        __syncthreads();   // smem reused for output staging

#pragma unroll
        for (int i = 0; i < 6; ++i) {
            const int nt  = wave + i * 4;
            const int col = nt * 16 + ln15;
            const float bs = bias_f[col];
            const int mat = col >> 7, c127 = col & 127;
            const int ocol = (mat == 0) ? c127
                           : 128 + 8 * (c127 >> 2) + (c127 & 3) + ((mat == 2) ? 4 : 0);

            bf16x8 bfr[4];
#pragma unroll
            for (int s = 0; s < 4; ++s)
                bfr[s] = *(const bf16x8*)(Wfrag + ((size_t)(nt * 4 + s) * 64 + lane) * 8);

#pragma unroll
            for (int ms = 0; ms < 4; ++ms) {
                f32x4 acc = {0.f, 0.f, 0.f, 0.f};
#pragma unroll
                for (int s = 0; s < 4; ++s)
                    acc = __builtin_amdgcn_mfma_f32_16x16x32_bf16(afr[ms][s], bfr[s], acc, 0, 0, 0);
#pragma unroll
                for (int r = 0; r < 4; ++r) {
                    int rl = ms * 16 + qd * 4 + r;
                    smem[rl * OS_STRIDE + ocol] = f2bf(acc[r] + bs);
                }
            }
        }
        __syncthreads();

        for (int q = t; q < 1024; q += 256) {
            int row = q >> 4, c = q & 15;
            int grow = m0 + row;
            if (grow < N_NODES)
                ((uint4*)Qt)[grow * 16 + c] = *(const uint4*)&smem[row * OS_STRIDE + c * 8];
        }
        for (int q = t; q < 2048; q += 256) {
            int row = q >> 5, g = q & 31;
            int grow = m0 + row;
            if (grow < N_NODES)
                ((uint4*)KVt)[grow * 32 + g] = *(const uint4*)&smem[row * OS_STRIDE + 128 + g * 8];
        }
    }
}

// ---------------------------------------------------------------------------
// Fused run-gather + bucket sort + aggregation (byte-identical to R13).
// ---------------------------------------------------------------------------
__global__ __launch_bounds__(256) void bucket_agg_kernel(
    const unsigned short* __restrict__ Qt, const unsigned short* __restrict__ KVt,
    const unsigned int* __restrict__ packed, const unsigned int* __restrict__ offcnt,
    const int* __restrict__ flag, void* __restrict__ out)
{
    __shared__ unsigned int   lds_pk[BCAP];     // 4 KB (also scan scratch)
    __shared__ unsigned short lds_src[BCAP];    // 2 KB
    __shared__ int runoff[BH_BLOCKS], runcnt[BH_BLOCKS], runpfx[BH_BLOCKS];
    __shared__ int cnt16[16], base16[16], cur16[16];
    __shared__ int nb_s;

    const int sb = blockIdx.x;
    const int t  = threadIdx.x;

    if (t < 16) { cnt16[t] = 0; cur16[t] = 0; }
    if (t < BH_BLOCKS) {
        unsigned int oc = offcnt[(size_t)t * SUBB + sb];
        runoff[t] = t * BH_CHUNK + (int)(oc >> 16);
        runcnt[t] = (int)(oc & 0xffffu);
    }
    __syncthreads();

    {
        int* sm = (int*)lds_pk;
        int x = (t < BH_BLOCKS) ? runcnt[t] : 0;
        int v = x;
        sm[t] = v;
        __syncthreads();
        for (int s = 1; s < 256; s <<= 1) {
            int a = (t >= s) ? sm[t - s] : 0;
            __syncthreads();
            v += a;
            sm[t] = v;
            __syncthreads();
        }
        if (t < BH_BLOCKS) runpfx[t] = v - x;
        if (t == 255) nb_s = v;
        __syncthreads();
    }
    const int nb = min(nb_s, BCAP);

    for (int r = t; r < BH_BLOCKS; r += 256) {
        int ro = runoff[r], rc = runcnt[r], rp = runpfx[r];
        for (int j = 0; j < rc; ++j) {
            int dpos = rp + j;
            if (dpos < BCAP) {
                unsigned int pk = packed[ro + j];
                lds_pk[dpos] = pk;
                atomicAdd(&cnt16[(pk >> 16) & 15], 1);
            }
        }
    }
    __syncthreads();
    if (t == 0) {
        int acc = 0;
#pragma unroll
        for (int i = 0; i < 16; ++i) { base16[i] = acc; acc += cnt16[i]; }
    }
    __syncthreads();
    for (int j = t; j < nb; j += 256) {
        unsigned int pk = lds_pk[j];
        int dl = (pk >> 16) & 15;
        int pos = base16[dl] + atomicAdd(&cur16[dl], 1);
        lds_src[pos] = (unsigned short)(pk & 0xffffu);
    }
    __syncthreads();

    const int wave = t >> 6;
    const int lane = t & 63;
    const int half = lane >> 5;
    const int hl   = lane & 31;
    const uint4* KV4 = (const uint4*)KVt;
    const bool of32 = (*flag > 100);

    for (int dl = wave; dl < 16; dl += 4) {
        const int d = sb * 16 + dl;
        uint2 qw = ((const uint2*)Qt)[d * 32 + hl];
        const float q0 = u16tof(qw.x & 0xffffu), q1 = u16tof(qw.x >> 16);
        const float q2 = u16tof(qw.y & 0xffffu), q3 = u16tof(qw.y >> 16);
        const int off = base16[dl];
        const int n   = cnt16[dl];

        float a0 = 0.f, a1 = 0.f, a2 = 0.f, a3 = 0.f, zz = 0.f;

#define CONSUME(KV, SCMASK)                                                     \
        {                                                                       \
            float p = fmaf(u16tof((KV).x & 0xffffu), q0,                        \
                      fmaf(u16tof((KV).x >> 16), q1,                            \
                      fmaf(u16tof((KV).y & 0xffffu), q2,                        \
                           u16tof((KV).y >> 16) * q3)));                        \
            p += __shfl_xor(p, 1);                                              \
            p += __shfl_xor(p, 2);                                              \
            float sc = __expf(__builtin_amdgcn_fmed3f(p * 0.25f, -5.f, 5.f));   \
            sc *= (SCMASK);                                                     \
            a0 = fmaf(u16tof((KV).z & 0xffffu), sc, a0);                        \
            a1 = fmaf(u16tof((KV).z >> 16),     sc, a1);                        \
            a2 = fmaf(u16tof((KV).w & 0xffffu), sc, a2);                        \
            a3 = fmaf(u16tof((KV).w >> 16),     sc, a3);                        \
            zz += sc;                                                           \
        }

        int j = 0;
        for (; j + 8 <= n; j += 8) {
            int e[4];
#pragma unroll
            for (int u = 0; u < 4; ++u) e[u] = lds_src[off + j + 2 * u + half];
            uint4 kv[4];
#pragma unroll
            for (int u = 0; u < 4; ++u) kv[u] = KV4[e[u] * 32 + hl];
#pragma unroll
            for (int u = 0; u < 4; ++u) CONSUME(kv[u], 1.f)
        }
        for (; j + 2 <= n; j += 2) {
            int e = lds_src[off + j + half];
            uint4 kv = KV4[e * 32 + hl];
            CONSUME(kv, 1.f)
        }
        if (j < n) {
            int e = lds_src[off + j];
            uint4 kv = KV4[e * 32 + hl];
            CONSUME(kv, (half == 0) ? 1.f : 0.f)
        }
#undef CONSUME

        a0 += __shfl_xor(a0, 32);
        a1 += __shfl_xor(a1, 32);
        a2 += __shfl_xor(a2, 32);
        a3 += __shfl_xor(a3, 32);
        zz += __shfl_xor(zz, 32);

        const float inv = 1.f / (zz + 1e-6f);
        const float r0 = a0 * inv, r1 = a1 * inv, r2 = a2 * inv, r3 = a3 * inv;

        if (half == 0) {
            if (of32) {
                ((float4*)out)[d * 32 + hl] = make_float4(r0, r1, r2, r3);
            } else {
                unsigned int w0 = ((unsigned int)f2bf(r1) << 16) | f2bf(r0);
                unsigned int w1 = ((unsigned int)f2bf(r3) << 16) | f2bf(r2);
                ((uint2*)out)[d * 32 + hl] = make_uint2(w0, w1);
            }
        }
    }
}

// ---------------------------------------------------------------------------
extern "C" void kernel_launch(void* const* d_in, const int* in_sizes, int n_in,
                              void* d_out, int out_size, void* d_ws, size_t ws_size,
                              hipStream_t stream)
{
    const void* h  = d_in[0];
    const void* Wq = d_in[1];
    const void* bq = d_in[2];
    const void* Wk = d_in[3];
    const void* bk = d_in[4];
    const void* Wv = d_in[5];
    const void* bv = d_in[6];
    const int*  src = (const int*)d_in[7];
    const int*  dst = (const int*)d_in[8];

    const size_t NQ = (size_t)N_NODES * QKV_DIM;   // 6,400,000
    const size_t WFRAG_N = 24 * 4 * 64 * 8;        // 49,152
    const size_t PACKED_N = (size_t)BH_BLOCKS * BH_CHUNK;   // 1,605,632
    const size_t OFFCNT_N = (size_t)BH_BLOCKS * SUBB;       // 612,500

    const size_t need = 3 * NQ * 2 + WFRAG_N * 2 + 384 * 4 + 64
                      + PACKED_N * 4 + OFFCNT_N * 4;

    if (ws_size < need) {
        sentinel_kernel<<<(out_size + 255) / 256, 256, 0, stream>>>((unsigned short*)d_out, out_size);
        return;
    }

    unsigned short* Qt  = (unsigned short*)d_ws;
    unsigned short* KVt = Qt + NQ;
    unsigned short* Wfrag = KVt + 2 * NQ;
    float* bias_f = (float*)(Wfrag + WFRAG_N);
    int* flag     = (int*)(bias_f + 384);
    unsigned int* packed = (unsigned int*)(flag + 16);
    unsigned int* offcnt = packed + PACKED_N;

    prep_kernel<<<24, 256, 0, stream>>>((const unsigned short*)h,
        Wq, bq, Wk, bk, Wv, bv, flag, Wfrag, bias_f);

    fused_gs_kernel<<<FUSED_BLOCKS, 256, 0, stream>>>(h, Wfrag, bias_f, flag,
        Qt, KVt, src, dst, packed, offcnt);

    bucket_agg_kernel<<<SUBB, 256, 0, stream>>>(Qt, KVt, packed, offcnt, flag, d_out);
}